// Round 14
// baseline (181.494 us; speedup 1.0000x reference)
//
#include <hip/hip_runtime.h>
#include <math.h>

#define IDIM 2048
#define NE   64
#define TOPK 8
#define NB   16384
#define BM   64            // rows per block
#define BK   64            // k per staged tile
#define NCH  (IDIM / BK)   // 32 tiles
#define TAU  5e-4f

// ws float layout: [0..63] f counts, [64..127] p sums, [128] z sum,
//                  [129] (int) flag count, [130..130+NB) (int) flagged row list
// byte WSPLIT_BYTE..: pre-split W tile images (32 tiles x (16KB hi + 16KB lo)),
//                     laid out EXACTLY as the LDS W tile (swizzle baked in).
#define WS_CNT 129
#define WS_LIST 130
#define WSPLIT_BYTE 66560
#define WSPLIT_REQ  (WSPLIT_BYTE + NCH * 32768)

typedef __attribute__((ext_vector_type(8))) short bf16x8_t;  // 8 bf16 = 4 VGPRs
typedef __attribute__((ext_vector_type(4))) float f32x4_t;   // MFMA acc

#define MFMA __builtin_amdgcn_mfma_f32_16x16x32_bf16

// Workgroup barrier WITHOUT vmcnt drain: LDS ops fenced, global/DMA loads stay in flight.
#define LDS_BARRIER() do {                                   \
    asm volatile("s_waitcnt lgkmcnt(0)" ::: "memory");       \
    __builtin_amdgcn_sched_barrier(0);                       \
    __builtin_amdgcn_s_barrier();                            \
    __builtin_amdgcn_sched_barrier(0);                       \
} while (0)

__device__ __forceinline__ float softplusf(float v) {
    return (v > 0.f) ? (v + log1pf(expf(-v))) : log1pf(expf(v));
}
__device__ __forceinline__ double softplus_d(double v) {
    return (v > 0.0) ? (v + log1p(exp(-v))) : log1p(exp(v));
}

// deterministic RNE fp32 -> bf16 bits (bit math; used in prep + fallback)
__device__ __forceinline__ short f2bf(float f) {
    unsigned u = __float_as_uint(f);
    unsigned r = (u + 0x7FFFu + ((u >> 16) & 1u)) >> 16;
    return (short)r;
}
__device__ __forceinline__ float bf2f(short s) {
    return __uint_as_float(((unsigned)(unsigned short)s) << 16);
}

__device__ __forceinline__ void split8(const float4 v0, const float4 v1,
                                       bf16x8_t& H, bf16x8_t& L) {
    float fv[8] = {v0.x, v0.y, v0.z, v0.w, v1.x, v1.y, v1.z, v1.w};
    #pragma unroll
    for (int q = 0; q < 8; ++q) {
        short hb = f2bf(fv[q]);
        H[q] = hb;
        L[q] = f2bf(fv[q] - bf2f(hb));
    }
}

// HW packed split: 8 f32 -> hi/lo bf16 planes via v_cvt_pk_bf16_f32 (dst.lo=src0)
__device__ __forceinline__ void split8_pk(const float4 v0, const float4 v1,
                                          int4& H, int4& L) {
    float fv[8] = {v0.x, v0.y, v0.z, v0.w, v1.x, v1.y, v1.z, v1.w};
    int hp[4], lp[4];
    #pragma unroll
    for (int p = 0; p < 4; ++p) {
        float a = fv[2 * p], b = fv[2 * p + 1];
        int h;
        asm("v_cvt_pk_bf16_f32 %0, %1, %2" : "=v"(h) : "v"(a), "v"(b));
        float ra = a - __uint_as_float(((unsigned)h) << 16);
        float rb = b - __uint_as_float(((unsigned)h) & 0xFFFF0000u);
        int lo_;
        asm("v_cvt_pk_bf16_f32 %0, %1, %2" : "=v"(lo_) : "v"(ra), "v"(rb));
        hp[p] = h; lp[p] = lo_;
    }
    H = (int4){hp[0], hp[1], hp[2], hp[3]};
    L = (int4){lp[0], lp[1], lp[2], lp[3]};
}

__device__ __forceinline__ void cvt_slot(const float4 v0, const float4 v1,
                                         char* hiP, char* loP, int off) {
    bf16x8_t H, L;
    split8(v0, v1, H, L);
    *(bf16x8_t*)(hiP + off) = H;
    *(bf16x8_t*)(loP + off) = L;
}

__global__ void init_ws_kernel(float* ws) {
    int t = threadIdx.x;
    if (t < WS_LIST) ws[t] = 0.0f;
}

// ---------------- pass 0: init ws + pre-split W into swizzled LDS tile images ----------------
// tile t (32KB): hi byte (col*128 + wslot*16) holds k-group (wslot ^ (col&7)); lo at +16384
__global__ __launch_bounds__(256) void prep_kernel(
    const float* __restrict__ Wg, const float* __restrict__ Wn,
    char* __restrict__ wsW, float* __restrict__ ws)
{
    if (blockIdx.x == 128) {             // merged init
        if (threadIdx.x < WS_LIST) ws[threadIdx.x] = 0.0f;
        return;
    }
    int g = blockIdx.x * 256 + threadIdx.x;   // 0..32767
    int t = g >> 10, i = g & 1023;
    int col = i >> 3, wslot = i & 7;
    int kslot = wslot ^ (col & 7);
    const float* src = (col < 64 ? Wg + (size_t)col * IDIM
                                 : Wn + (size_t)(col - 64) * IDIM) + t * BK + kslot * 8;
    float4 v0 = *(const float4*)src;
    float4 v1 = *(const float4*)(src + 4);
    bf16x8_t H, L;
    split8(v0, v1, H, L);
    char* dst = wsW + (size_t)t * 32768;
    *(bf16x8_t*)(dst + i * 16)         = H;
    *(bf16x8_t*)(dst + 16384 + i * 16) = L;
}

// ---------------- pass 1: split-bf16 MFMA GEMM (32x32/wave), DMA W staging + gating ----------------
// LDS (98304B): abuf[c]@c*16384 (AH 8K + AL 8K), wbuf[c]@32768+c*32768 (WH 16K + WL 16K)
//   epilogue alias: sL f32[64][132] @0 (33792B); sP@33792 sF@34048 sZ@34304 (byte offsets)
template<bool PRE>
__global__ __launch_bounds__(512, 2) void gate_main_kernel(
    const float* __restrict__ x, const float* __restrict__ noise,
    const float* __restrict__ Wg, const float* __restrict__ bg,
    const float* __restrict__ Wn, const char* __restrict__ wsW,
    float* __restrict__ out_w, float* __restrict__ out_i,
    float* __restrict__ ws, int listCap)
{
    __shared__ char smem[98304] __attribute__((aligned(16)));

    const int u   = threadIdx.x;
    const int w   = u >> 6;              // wave 0..7
    const int wr  = w >> 2;              // row half: rows [wr*32, wr*32+32)
    const int wc  = w & 3;               // col quarter: cols [wc*32, wc*32+32)
    const int l   = u & 63;
    const int lr  = l & 15;
    const int lg4 = l >> 4;
    const int s7  = lr & 7;
    const int row0 = blockIdx.x * BM;

    // A staging: 512 threads, one 16B hi + 16B lo slot each (swizzle-baked source)
    const int arow = u >> 3;             // 0..63
    const int aslot = u & 7;
    const int agrp = aslot ^ (arow & 7);
    const float* paA = x + (size_t)(row0 + arow) * IDIM + agrp * 8;
    const int aoff = arow * 128 + aslot * 16;

    // W DMA offsets (PRE): each wave stages its 4KB slice of the 32KB tile
    const int dmaL = w * 4096;           // wave-uniform LDS offset within wbuf
    const int dmaG = dmaL + l * 16;      // per-lane global offset within image tile

    // fallback W staging: thread u stages col = u>>2, slots {2q, 2q+1}, q = u&3
    const int fcol = u >> 2;
    const int fq   = u & 3;
    const float* pw = (fcol < 64 ? Wg + (size_t)fcol * IDIM
                                 : Wn + (size_t)(fcol - 64) * IDIM);

    f32x4_t acc[2][2];
    #pragma unroll
    for (int rt = 0; rt < 2; ++rt)
        #pragma unroll
        for (int ct = 0; ct < 2; ++ct) {
            f32x4_t z = {0.f, 0.f, 0.f, 0.f};
            acc[rt][ct] = z;
        }

    float4 rA0, rA1;

#define LOADA(tt) { rA0 = *(const float4*)(paA + (tt) * BK); \
                    rA1 = *(const float4*)(paA + (tt) * BK + 4); }

#define CVTA(bufi) do {                                         \
    char* ab_ = smem + (bufi) * 16384;                          \
    int4 H_, L_;                                                \
    split8_pk(rA0, rA1, H_, L_);                                \
    *(int4*)(ab_ + aoff)        = H_;                           \
    *(int4*)(ab_ + 8192 + aoff) = L_;                           \
} while (0)

#define DMAW(tt, bufi) do {                                                     \
    const char* img_ = wsW + (size_t)(tt) * 32768 + dmaG;                       \
    char* wb_ = smem + 32768 + (bufi) * 32768 + dmaL;                           \
    _Pragma("unroll")                                                           \
    for (int j_ = 0; j_ < 4; ++j_)                                              \
        __builtin_amdgcn_global_load_lds(                                       \
            (const __attribute__((address_space(1))) void*)(img_ + j_ * 1024),  \
            (__attribute__((address_space(3))) void*)(wb_ + j_ * 1024),         \
            16, 0, 0);                                                          \
} while (0)

#define FSTAGE(tt, bufi) do {                                   \
    char* wb_ = smem + 32768 + (bufi) * 32768;                  \
    _Pragma("unroll")                                           \
    for (int s_ = 2 * fq; s_ <= 2 * fq + 1; ++s_) {             \
        int kg_ = s_ ^ (fcol & 7);                              \
        float4 v0_ = *(const float4*)(pw + (tt) * BK + kg_ * 8);    \
        float4 v1_ = *(const float4*)(pw + (tt) * BK + kg_ * 8 + 4);\
        cvt_slot(v0_, v1_, wb_, wb_ + 16384, fcol * 128 + s_ * 16); \
    }                                                           \
} while (0)

    // ---- prologue: stage tile 0 (A+W), issue tile-1 loads ----
    LOADA(0);
    CVTA(0);                             // auto-waits A(0)
    if constexpr (PRE) {
        DMAW(0, 0);
        LOADA(1);
        DMAW(1, 1);
        // queue: DMA0[4] + A1[2] + DMA1[4] = 10; drain DMA0 -> 6 remain
        asm volatile("s_waitcnt vmcnt(6)" ::: "memory");
        __builtin_amdgcn_sched_barrier(0);
    } else {
        FSTAGE(0, 0);
        FSTAGE(1, 1);
        LOADA(1);
    }
    LDS_BARRIER();

    int cur = 0;
    for (int t = 0; t < NCH; ++t, cur ^= 1) {
        // ---- compute tile t: 32x32 per wave ----
        {
            char* ab = smem + cur * 16384;
            char* wb = smem + 32768 + cur * 32768;
            #pragma unroll
            for (int ks = 0; ks < 2; ++ks) {
                const int so = (((ks * 4 + lg4) ^ s7) << 4);
                bf16x8_t ah[2], al_[2], bh[2], bl[2];
                #pragma unroll
                for (int rt = 0; rt < 2; ++rt) {
                    const int ro = (wr * 32 + rt * 16 + lr) * 128 + so;
                    ah[rt]  = *(const bf16x8_t*)(ab + ro);
                    al_[rt] = *(const bf16x8_t*)(ab + 8192 + ro);
                }
                #pragma unroll
                for (int ct = 0; ct < 2; ++ct) {
                    const int co = (wc * 32 + ct * 16 + lr) * 128 + so;
                    bh[ct] = *(const bf16x8_t*)(wb + co);
                    bl[ct] = *(const bf16x8_t*)(wb + 16384 + co);
                }
                #pragma unroll
                for (int rt = 0; rt < 2; ++rt)
                    #pragma unroll
                    for (int ct = 0; ct < 2; ++ct) {
                        acc[rt][ct] = MFMA(ah[rt],  bh[ct], acc[rt][ct], 0, 0, 0);
                        acc[rt][ct] = MFMA(ah[rt],  bl[ct], acc[rt][ct], 0, 0, 0);
                        acc[rt][ct] = MFMA(al_[rt], bh[ct], acc[rt][ct], 0, 0, 0);
                    }
            }
        }
        if (t + 1 == NCH) break;
        LDS_BARRIER();                   // all reads of bufs[cur] done
        CVTA(cur ^ 1);                   // A(t+1): auto vmcnt also confirms DMA(t+1)
        if (t + 2 < NCH) {
            if constexpr (PRE) DMAW(t + 2, cur); else FSTAGE(t + 2, cur);
            LOADA(t + 2);                // stays in flight across barrier + compute(t+1)
        }
        LDS_BARRIER();                   // A(t+1) writes visible; DMA(t+1) drained by all
    }
    __syncthreads();                     // full drain; staging dead; safe to alias

    // ---- epilogue: acc -> sL[64][132]  (C/D: col=lane&15, row=(lane>>4)*4+reg) ----
    float* sL = (float*)smem;
    float* sP = (float*)(smem + 33792);
    float* sF = (float*)(smem + 34048);
    float* sZ = (float*)(smem + 34304);
    if (u < NE) { sP[u] = 0.f; sF[u] = 0.f; }
    if (u == 0) sZ[0] = 0.f;
    #pragma unroll
    for (int rt = 0; rt < 2; ++rt)
        #pragma unroll
        for (int ct = 0; ct < 2; ++ct)
            #pragma unroll
            for (int r = 0; r < 4; ++r)
                sL[(wr * 32 + rt * 16 + lg4 * 4 + r) * 132 + (wc * 32 + ct * 16 + lr)]
                    = acc[rt][ct][r];
    __syncthreads();

    // ---- gating: 8 waves x 8 rows, lane = expert ----
    const float bgl = bg[l];
    float pacc = 0.f, zacc = 0.f;
    #pragma unroll 1
    for (int rr = 0; rr < 8; ++rr) {
        const int r = w * 8 + rr;
        const int grow = row0 + r;
        float lg   = sL[r * 132 + l] + bgl;
        float npre = sL[r * 132 + 64 + l];
        float vcur = fmaf(noise[(size_t)grow * NE + l], softplusf(npre), lg);

        float tkv[9]; int tki[9];
        #pragma unroll
        for (int k = 0; k < 9; ++k) {
            float mv = vcur; int mi = l;
            #pragma unroll
            for (int o = 32; o > 0; o >>= 1) {
                float ov = __shfl_xor(mv, o);
                int   oi = __shfl_xor(mi, o);
                if (ov > mv || (ov == mv && oi < mi)) { mv = ov; mi = oi; }
            }
            tkv[k] = mv; tki[k] = mi;
            if (l == mi) vcur = -1e30f;
        }

        float m0 = tkv[0], s = 0.f, wk[TOPK];
        #pragma unroll
        for (int k = 0; k < TOPK; ++k) { wk[k] = expf(tkv[k] - m0); s += wk[k]; }
        float inv = 1.f / s;
        float myw = 0.f; int myi = 0;
        #pragma unroll
        for (int k = 0; k < TOPK; ++k)
            if (l == k) { myw = wk[k] * inv; myi = tki[k]; }
        if (l < TOPK) {
            out_w[(size_t)grow * TOPK + l] = myw;
            out_i[(size_t)grow * TOPK + l] = (float)myi;
        }

        if (l == 0) {
            atomicAdd(&sF[tki[0]], 1.f);
            float ming = 1e30f;
            #pragma unroll
            for (int k = 0; k < 8; ++k) ming = fminf(ming, tkv[k] - tkv[k + 1]);
            if (ming < TAU) {
                int slot = atomicAdd((int*)&ws[WS_CNT], 1);
                if (slot < listCap) ((int*)ws)[WS_LIST + slot] = grow;
            }
        }

        float rm = lg;
        #pragma unroll
        for (int o = 32; o > 0; o >>= 1) rm = fmaxf(rm, __shfl_xor(rm, o));
        float pe = expf(lg - rm);
        float ssum = pe;
        #pragma unroll
        for (int o = 32; o > 0; o >>= 1) ssum += __shfl_xor(ssum, o);
        pacc += pe / ssum;
        if (l == 0) { float lse = rm + logf(ssum); zacc += lse * lse; }
    }

    atomicAdd(&sP[l], pacc);
    if (l == 0) atomicAdd(sZ, zacc);
    __syncthreads();
    if (u < NE) {
        atomicAdd(&ws[u],      sF[u]);
        atomicAdd(&ws[NE + u], sP[u]);
    }
    if (u == 0) atomicAdd(&ws[2 * NE], sZ[0]);
}

// ---------------- pass 2: finalize scalars (block 0) + fp64 recheck, 1 row/block ----------------
__global__ __launch_bounds__(512) void recheck_finalize_kernel(
    const float* __restrict__ x, const float* __restrict__ noise,
    const float* __restrict__ Wg, const float* __restrict__ bg,
    const float* __restrict__ Wn,
    float* __restrict__ out_w, float* __restrict__ out_i, float* __restrict__ out_s,
    const float* __restrict__ ws, int listCap)
{
    __shared__ double sRed[512];
    const int t = threadIdx.x;

    if (blockIdx.x == 0 && t < 64) {
        float v = (ws[t] / (float)NB) * (ws[NE + t] / (float)NB);
        #pragma unroll
        for (int o = 32; o > 0; o >>= 1) v += __shfl_down(v, o);
        if (t == 0) {
            out_s[0] = (float)NE * v;
            out_s[1] = ws[2 * NE] / (float)NB;
        }
    }

    const int* wsi = (const int*)ws;
    int cnt = wsi[WS_CNT];
    if (cnt > listCap) cnt = listCap;
    if (cnt <= 0) return;

    const int slot = t & 127;
    const int q4   = t >> 7;
    const float* wrb = ((slot < 64) ? (Wg + (size_t)slot * IDIM)
                                    : (Wn + (size_t)(slot - 64) * IDIM)) + q4 * 512;

    for (int bi = blockIdx.x; bi < cnt; bi += gridDim.x) {
        const int row = wsi[WS_LIST + bi];
        const float* xr = x + (size_t)row * IDIM + q4 * 512;

        double a = 0.0;
        #pragma unroll 4
        for (int k = 0; k < 512; k += 4) {
            float4 wv = *(const float4*)(wrb + k);
            float4 xv = *(const float4*)(xr + k);
            a = fma((double)xv.x, (double)wv.x, a);
            a = fma((double)xv.y, (double)wv.y, a);
            a = fma((double)xv.z, (double)wv.z, a);
            a = fma((double)xv.w, (double)wv.w, a);
        }
        sRed[t] = a;
        __syncthreads();
        if (t < 128)
            sRed[t] = sRed[t] + sRed[t + 128] + sRed[t + 256] + sRed[t + 384];
        __syncthreads();

        if (t < 64) {
            const int lane = t;
            double g = sRed[lane];
            double n = sRed[64 + lane];
            double lgd = g + (double)bg[lane];
            double nz = (double)noise[(size_t)row * NE + lane];
            double vcur = fma(nz, softplus_d(n), lgd);

            double tkv[TOPK]; int tki[TOPK];
            #pragma unroll
            for (int k = 0; k < TOPK; ++k) {
                double mv = vcur; int mi = lane;
                #pragma unroll
                for (int o = 32; o > 0; o >>= 1) {
                    double ov = __shfl_xor(mv, o);
                    int    oi = __shfl_xor(mi, o);
                    if (ov > mv || (ov == mv && oi < mi)) { mv = ov; mi = oi; }
                }
                tkv[k] = mv; tki[k] = mi;
                if (lane == mi) vcur = -1e300;
            }
            double m0 = tkv[0], s = 0.0, wk[TOPK];
            #pragma unroll
            for (int k = 0; k < TOPK; ++k) { wk[k] = exp(tkv[k] - m0); s += wk[k]; }
            double inv = 1.0 / s;
            float myw = 0.f; int myi = 0;
            #pragma unroll
            for (int k = 0; k < TOPK; ++k)
                if (lane == k) { myw = (float)(wk[k] * inv); myi = tki[k]; }
            if (lane < TOPK) {
                out_w[(size_t)row * TOPK + lane] = myw;
                out_i[(size_t)row * TOPK + lane] = (float)myi;
            }
        }
        __syncthreads();
    }
}

extern "C" void kernel_launch(void* const* d_in, const int* in_sizes, int n_in,
                              void* d_out, int out_size, void* d_ws, size_t ws_size,
                              hipStream_t stream) {
    const float* x     = (const float*)d_in[0];
    const float* noise = (const float*)d_in[1];
    const float* Wg    = (const float*)d_in[2];
    const float* bg    = (const float*)d_in[3];
    const float* Wn    = (const float*)d_in[4];
    float* out = (float*)d_out;
    float* ws  = (float*)d_ws;
    char*  wsW = (char*)d_ws + WSPLIT_BYTE;

    long cap = (long)(ws_size / 4) - WS_LIST;
    int listCap = (int)(cap < 0 ? 0 : (cap > NB ? NB : cap));
    const bool pre = ws_size >= (size_t)WSPLIT_REQ;

    if (pre) {
        hipLaunchKernelGGL(prep_kernel, dim3(129), dim3(256), 0, stream, Wg, Wn, wsW, ws);
        hipLaunchKernelGGL(gate_main_kernel<true>, dim3(NB / BM), dim3(512), 0, stream,
                           x, noise, Wg, bg, Wn, wsW,
                           out, out + (size_t)NB * TOPK, ws, listCap);
    } else {
        hipLaunchKernelGGL(init_ws_kernel, dim3(1), dim3(256), 0, stream, ws);
        hipLaunchKernelGGL(gate_main_kernel<false>, dim3(NB / BM), dim3(512), 0, stream,
                           x, noise, Wg, bg, Wn, wsW,
                           out, out + (size_t)NB * TOPK, ws, listCap);
    }
    hipLaunchKernelGGL(recheck_finalize_kernel, dim3(1024), dim3(512), 0, stream,
                       x, noise, Wg, bg, Wn,
                       out, out + (size_t)NB * TOPK, out + 2 * (size_t)NB * TOPK,
                       ws, listCap);
}